// Round 1
// baseline (12954.025 us; speedup 1.0000x reference)
//
#include <hip/hip_runtime.h>
#include <math.h>

#define BB 64
#define SS 1024
#define CC 512
#define VV 140
#define AA 512
#define HH 512
#define TT 128
#define G4 2048   // 4*H
#define VA 652    // V+A

// ---------------------------------------------------------------------------
// One-time precompute kernels
// ---------------------------------------------------------------------------

// p0[c] = sum_a Hcb[a]*Ic[a][c]; v0[k] = sum_a Hc[a][k]*Icb[a]; s0 = Hcb.Icb
__global__ void k_small(const float* __restrict__ Hc, const float* __restrict__ Hcb,
                        const float* __restrict__ Ic, const float* __restrict__ Icb,
                        float* __restrict__ p0, float* __restrict__ v0,
                        float* __restrict__ s0) {
    int t = threadIdx.x;  // 512
    float av = 0.f, pv = 0.f;
    for (int a = 0; a < AA; a++) {
        av += Hc[a * HH + t] * Icb[a];
        pv += Hcb[a] * Ic[a * CC + t];
    }
    v0[t] = av;
    p0[t] = pv;
    if (t == 0) {
        float s = 0.f;
        for (int a = 0; a < AA; a++) s += Hcb[a] * Icb[a];
        s0[0] = s;
    }
}

// P[k][c] = sum_a Hc[a][k] * Ic[a][c]     (P = Hc^T Ic, [512][512])
__global__ __launch_bounds__(256) void k_P(const float* __restrict__ Hc,
                                           const float* __restrict__ Ic,
                                           float* __restrict__ P) {
    int k = blockIdx.y;
    int c = blockIdx.x * 256 + threadIdx.x;
    float acc = 0.f;
    for (int a = 0; a < AA; a++) acc += Hc[a * HH + k] * Ic[a * CC + c];
    P[k * CC + c] = acc;
}

// Gtmp[g][c] = sum_a Wih[g][140+a] * Ic[a][c]   ([2048][512])
__global__ __launch_bounds__(256) void k_G(const float* __restrict__ Wih,
                                           const float* __restrict__ Ic,
                                           float* __restrict__ Gtmp) {
    int gb = blockIdx.y * 8;
    int c = blockIdx.x * 256 + threadIdx.x;
    float acc[8];
#pragma unroll
    for (int j = 0; j < 8; j++) acc[j] = 0.f;
    for (int a = 0; a < AA; a++) {
        float ic = Ic[a * CC + c];
#pragma unroll
        for (int j = 0; j < 8; j++) acc[j] += Wih[(size_t)(gb + j) * VA + VV + a] * ic;
    }
#pragma unroll
    for (int j = 0; j < 8; j++) Gtmp[(size_t)(gb + j) * CC + c] = acc[j];
}

// gate_bias[g] = b_ih[g] + b_hh[g] + sum_a Wih[g][140+a]*Icb[a]
__global__ void k_gate_bias(const float* __restrict__ Wih, const float* __restrict__ Icb,
                            const float* __restrict__ bih, const float* __restrict__ bhh,
                            float* __restrict__ gate_bias) {
    int g = blockIdx.x * 256 + threadIdx.x;
    float acc = bih[g] + bhh[g];
    for (int a = 0; a < AA; a++) acc += Wih[(size_t)g * VA + VV + a] * Icb[a];
    gate_bias[g] = acc;
}

// dst[c*R + r] = src[r*ld + col0 + c]  (tiled transpose)
__global__ void k_transpose(const float* __restrict__ src, float* __restrict__ dst,
                            int R, int Cc, int ld, int col0) {
    __shared__ float tile[32][33];
    int r0 = blockIdx.y * 32, c0 = blockIdx.x * 32;
    int tx = threadIdx.x, ty = threadIdx.y;  // 32 x 8
#pragma unroll
    for (int k = 0; k < 4; k++) {
        int r = r0 + ty + k * 8, c = c0 + tx;
        if (r < R && c < Cc) tile[ty + k * 8][tx] = src[(size_t)r * ld + col0 + c];
    }
    __syncthreads();
#pragma unroll
    for (int k = 0; k < 4; k++) {
        int c = c0 + ty + k * 8, r = r0 + tx;
        if (c < Cc && r < R) dst[(size_t)c * R + r] = tile[tx][ty + k * 8];
    }
}

// h=c=0, q' = p0, qb = s0, char = labels[:,0]
__global__ void k_init(const int* __restrict__ labels, const float* __restrict__ p0,
                       const float* __restrict__ s0, float* __restrict__ h,
                       float* __restrict__ cst, float* __restrict__ qp,
                       float* __restrict__ qb, int* __restrict__ charr) {
    int b = blockIdx.x, t = threadIdx.x;  // 64 x 512
    h[b * HH + t] = 0.f;
    cst[b * HH + t] = 0.f;
    qp[b * CC + t] = p0[t];
    if (t == 0) {
        qb[b] = s0[0];
        charr[b] = labels[b * TT];
    }
}

// ---------------------------------------------------------------------------
// Per-step kernels
// ---------------------------------------------------------------------------

// Flash attention pass over X. grid (4 chunks, 64 b), 512 threads (8 waves).
// Each wave handles 32 rows; per row: dot(q', X_row) -> online softmax update
// accumulating acc_c = sum exp(score-m) * X_row[c] with X row still in regs.
__global__ __launch_bounds__(512) void k_flash(const float* __restrict__ X,
                                               const float* __restrict__ qp,
                                               const float* __restrict__ qb,
                                               float* __restrict__ part_m,
                                               float* __restrict__ part_l,
                                               float* __restrict__ part_acc) {
    int b = blockIdx.y, chunk = blockIdx.x;
    int tid = threadIdx.x, w = tid >> 6, lane = tid & 63;
    const float inv_sqrt_a = 0.044194173824159216f;  // 1/sqrt(512)

    const float4* q4 = (const float4*)(qp + b * CC) + lane * 2;
    float4 qa = q4[0], qb4 = q4[1];
    float qoff = qb[b];

    float m = -INFINITY, l = 0.f;
    float acc[8];
#pragma unroll
    for (int j = 0; j < 8; j++) acc[j] = 0.f;

    int s0 = chunk * 256 + w * 32;
    for (int i = 0; i < 32; i++) {
        const float4* xr = (const float4*)(X + ((size_t)b * SS + (s0 + i)) * CC) + lane * 2;
        float4 x0 = xr[0], x1 = xr[1];
        float xv[8];
        xv[0] = x0.x; xv[1] = x0.y; xv[2] = x0.z; xv[3] = x0.w;
        xv[4] = x1.x; xv[5] = x1.y; xv[6] = x1.z; xv[7] = x1.w;
        float d = xv[0] * qa.x + xv[1] * qa.y + xv[2] * qa.z + xv[3] * qa.w +
                  xv[4] * qb4.x + xv[5] * qb4.y + xv[6] * qb4.z + xv[7] * qb4.w;
#pragma unroll
        for (int off = 1; off < 64; off <<= 1) d += __shfl_xor(d, off, 64);
        float score = (d + qoff) * inv_sqrt_a;
        if (score > m) {  // wave-uniform branch (d identical across lanes)
            float f = expf(m - score);  // expf(-inf)=0 on first iteration
            l = l * f + 1.f;
#pragma unroll
            for (int j = 0; j < 8; j++) acc[j] = acc[j] * f + xv[j];
            m = score;
        } else {
            float p = expf(score - m);
            l += p;
#pragma unroll
            for (int j = 0; j < 8; j++) acc[j] += p * xv[j];
        }
    }

    // combine 8 waves -> one block partial
    __shared__ float lm[8], ll[8];
    __shared__ __align__(16) float lacc[8][512];
    if (lane == 0) lm[w] = m;
    __syncthreads();
    float M = lm[0];
#pragma unroll
    for (int j = 1; j < 8; j++) M = fmaxf(M, lm[j]);
    float f = expf(m - M);
    if (lane == 0) ll[w] = l * f;
#pragma unroll
    for (int j = 0; j < 8; j++) lacc[w][lane * 8 + j] = acc[j] * f;
    __syncthreads();
    float s = 0.f;
#pragma unroll
    for (int j = 0; j < 8; j++) s += lacc[j][tid];
    part_acc[((b * 4 + chunk) << 9) + tid] = s;
    if (tid == 0) {
        float lt = 0.f;
        for (int j = 0; j < 8; j++) lt += ll[j];
        part_m[b * 4 + chunk] = M;
        part_l[b * 4 + chunk] = lt;
    }
}

// Skinny GEMM: pg[cs][b][g] partial of  ywx.G^T (cs 0..3)  or  h.Whh^T (cs 4..7).
// grid (cs=8, gt=8, bt=4), 256 threads; thread computes 4b x 4g register tile.
__global__ __launch_bounds__(256) void k_gates(const float* __restrict__ part_m,
                                               const float* __restrict__ part_l,
                                               const float* __restrict__ part_acc,
                                               const float* __restrict__ h,
                                               const float* __restrict__ GT,
                                               const float* __restrict__ WhhT,
                                               float* __restrict__ pg) {
    int cs = blockIdx.x, gt = blockIdx.y, bt = blockIdx.z;
    int tid = threadIdx.x;
    int tg = tid & 63, tb = tid >> 6;

    __shared__ __align__(16) float actT[128 * 16];  // [cc][bb]
    __shared__ float coefL[16][4];
    __shared__ __align__(16) float wbuf[32 * 256];

    if (cs < 4) {
        if (tid < 16) {
            int b = bt * 16 + tid;
            float m0 = part_m[b * 4 + 0], m1 = part_m[b * 4 + 1];
            float m2 = part_m[b * 4 + 2], m3 = part_m[b * 4 + 3];
            float M = fmaxf(fmaxf(m0, m1), fmaxf(m2, m3));
            float e0 = expf(m0 - M), e1 = expf(m1 - M), e2 = expf(m2 - M), e3 = expf(m3 - M);
            float denom = e0 * part_l[b * 4 + 0] + e1 * part_l[b * 4 + 1] +
                          e2 * part_l[b * 4 + 2] + e3 * part_l[b * 4 + 3];
            float inv = 1.f / denom;
            coefL[tid][0] = e0 * inv; coefL[tid][1] = e1 * inv;
            coefL[tid][2] = e2 * inv; coefL[tid][3] = e3 * inv;
        }
        __syncthreads();
#pragma unroll
        for (int k = 0; k < 8; k++) {
            int idx = k * 256 + tid;
            int bb = idx >> 7, cc = idx & 127;
            int b = bt * 16 + bb;
            const float* pa = part_acc + (size_t)(b * 4) * 512 + cs * 128 + cc;
            float v = coefL[bb][0] * pa[0] + coefL[bb][1] * pa[512] +
                      coefL[bb][2] * pa[1024] + coefL[bb][3] * pa[1536];
            actT[cc * 16 + bb] = v;
        }
    } else {
#pragma unroll
        for (int k = 0; k < 8; k++) {
            int idx = k * 256 + tid;
            int bb = idx >> 7, cc = idx & 127;
            actT[cc * 16 + bb] = h[(bt * 16 + bb) * HH + (cs - 4) * 128 + cc];
        }
    }

    const float* W = (cs < 4) ? (GT + (size_t)(cs * 128) * G4)
                              : (WhhT + (size_t)((cs - 4) * 128) * G4);
    float4 acc0 = make_float4(0, 0, 0, 0), acc1 = make_float4(0, 0, 0, 0);
    float4 acc2 = make_float4(0, 0, 0, 0), acc3 = make_float4(0, 0, 0, 0);

#define FMA4(accv, sclr, wv)                    \
    accv.x += (sclr) * wv.x; accv.y += (sclr) * wv.y; \
    accv.z += (sclr) * wv.z; accv.w += (sclr) * wv.w;

    for (int cchunk = 0; cchunk < 4; cchunk++) {
        __syncthreads();
#pragma unroll
        for (int k = 0; k < 32; k++) {
            int idx = k * 256 + tid;
            int i = idx >> 8, j = idx & 255;
            wbuf[idx] = W[(size_t)(cchunk * 32 + i) * G4 + gt * 256 + j];
        }
        __syncthreads();
#pragma unroll 4
        for (int i = 0; i < 32; i++) {
            float4 wv = *(const float4*)&wbuf[i * 256 + tg * 4];
            float4 av = *(const float4*)&actT[(cchunk * 32 + i) * 16 + tb * 4];
            FMA4(acc0, av.x, wv);
            FMA4(acc1, av.y, wv);
            FMA4(acc2, av.z, wv);
            FMA4(acc3, av.w, wv);
        }
    }
#undef FMA4

    int b0 = bt * 16 + tb * 4;
    int g0 = gt * 256 + tg * 4;
    *(float4*)&pg[(size_t)(cs * BB + b0 + 0) * G4 + g0] = acc0;
    *(float4*)&pg[(size_t)(cs * BB + b0 + 1) * G4 + g0] = acc1;
    *(float4*)&pg[(size_t)(cs * BB + b0 + 2) * G4 + g0] = acc2;
    *(float4*)&pg[(size_t)(cs * BB + b0 + 3) * G4 + g0] = acc3;
}

// Per-b: sum gate partials + bias + Wih[:,char]; LSTM activations; logits;
// argmax (first-index, numpy semantics); next-step q' = h.P + p0, qb = h.v0+s0.
__global__ __launch_bounds__(256) void k_update(
    const float* __restrict__ pg, const float* __restrict__ gate_bias,
    const float* __restrict__ Wih0T, const float* __restrict__ Wout,
    const float* __restrict__ bout, const float* __restrict__ P,
    const float* __restrict__ p0, const float* __restrict__ v0,
    const float* __restrict__ s0, float* __restrict__ h, float* __restrict__ cst,
    float* __restrict__ qp, float* __restrict__ qb, int* __restrict__ charr,
    float* __restrict__ out, int t) {
    int b = blockIdx.x, tid = threadIdx.x;
    __shared__ float gl[G4];
    __shared__ __align__(16) float hl[HH];
    __shared__ float logl[VV];

    int ch = charr[b];  // read before (later) overwrite; safe: write is after syncs

    // 1. gates
#pragma unroll
    for (int k = 0; k < 8; k++) {
        int g = k * 256 + tid;
        float a = gate_bias[g] + Wih0T[(size_t)ch * G4 + g];
#pragma unroll
        for (int j = 0; j < 8; j++) a += pg[(size_t)(j * BB + b) * G4 + g];
        gl[g] = a;
    }
    __syncthreads();

    // 2. LSTM cell
#pragma unroll
    for (int k = 0; k < 2; k++) {
        int idx = k * 256 + tid;
        float ig = 1.f / (1.f + expf(-gl[idx]));
        float fg = 1.f / (1.f + expf(-gl[512 + idx]));
        float gg = tanhf(gl[1024 + idx]);
        float og = 1.f / (1.f + expf(-gl[1536 + idx]));
        float cn = fg * cst[b * HH + idx] + ig * gg;
        float hn = og * tanhf(cn);
        cst[b * HH + idx] = cn;
        h[b * HH + idx] = hn;
        hl[idx] = hn;
    }
    __syncthreads();

    // 3. logits (4 waves, wave-parallel dot over 512)
    int w = tid >> 6, lane = tid & 63;
    const float4* hr = (const float4*)hl + lane * 2;
    float4 h0 = hr[0], h1 = hr[1];
    for (int v = w; v < VV; v += 4) {
        const float4* wr = (const float4*)(Wout + (size_t)v * HH) + lane * 2;
        float4 w0 = wr[0], w1 = wr[1];
        float d = w0.x * h0.x + w0.y * h0.y + w0.z * h0.z + w0.w * h0.w +
                  w1.x * h1.x + w1.y * h1.y + w1.z * h1.z + w1.w * h1.w;
#pragma unroll
        for (int off = 1; off < 64; off <<= 1) d += __shfl_xor(d, off, 64);
        if (lane == 0) {
            d += bout[v];
            logl[v] = d;
            out[((size_t)b * TT + t) * VV + v] = d;
        }
    }
    __syncthreads();

    // 4. argmax (first max, numpy tie-break)
    if (tid == 0) {
        float best = logl[0];
        int bi = 0;
        for (int v = 1; v < VV; v++) {
            float x = logl[v];
            if (x > best) { best = x; bi = v; }
        }
        charr[b] = bi;
    }

    // 5. q' for next step: q'[c] = sum_k hl[k]*P[k][c] + p0[c]
    {
        int c0 = tid, c1 = tid + 256;
        float a0 = p0[c0], a1 = p0[c1];
#pragma unroll 4
        for (int k = 0; k < HH; k++) {
            float hk = hl[k];
            a0 += hk * P[k * CC + c0];
            a1 += hk * P[k * CC + c1];
        }
        qp[b * CC + c0] = a0;
        qp[b * CC + c1] = a1;
    }
    // qb = h.v0 + s0 (wave 0)
    if (w == 0) {
        float p = 0.f;
#pragma unroll
        for (int j = 0; j < 8; j++) {
            int k = lane + 64 * j;
            p += hl[k] * v0[k];
        }
#pragma unroll
        for (int off = 1; off < 64; off <<= 1) p += __shfl_xor(p, off, 64);
        if (lane == 0) qb[b] = p + s0[0];
    }
}

// ---------------------------------------------------------------------------

extern "C" void kernel_launch(void* const* d_in, const int* in_sizes, int n_in,
                              void* d_out, int out_size, void* d_ws, size_t ws_size,
                              hipStream_t stream) {
    const float* X    = (const float*)d_in[0];   // [64,1024,512]
    const int*   lab  = (const int*)d_in[1];     // [64,128]
    const float* Icw  = (const float*)d_in[2];   // [512,512]
    const float* Icb  = (const float*)d_in[3];   // [512]
    const float* Hcw  = (const float*)d_in[4];   // [512,512]
    const float* Hcb  = (const float*)d_in[5];   // [512]
    const float* Wih  = (const float*)d_in[6];   // [2048,652]
    const float* bih  = (const float*)d_in[7];   // [2048]
    const float* Whh  = (const float*)d_in[8];   // [2048,512]
    const float* bhh  = (const float*)d_in[9];   // [2048]
    const float* Wout = (const float*)d_in[10];  // [140,512]
    const float* bout = (const float*)d_in[11];  // [140]
    float* out = (float*)d_out;                  // [64,128,140]

    // workspace layout (floats)
    float* ws = (float*)d_ws;
    size_t off = 0;
    float* P        = ws + off; off += 512 * 512;
    float* GT       = ws + off; off += 512 * 2048;
    float* WhhT     = ws + off; off += 512 * 2048;
    float* Wih0T    = ws + off; off += 140 * 2048;
    float* gateb    = ws + off; off += 2048;
    float* p0       = ws + off; off += 512;
    float* v0       = ws + off; off += 512;
    float* s0       = ws + off; off += 64;
    float* h        = ws + off; off += 64 * 512;
    float* cst      = ws + off; off += 64 * 512;
    float* qp       = ws + off; off += 64 * 512;
    float* qb       = ws + off; off += 64;
    float* part_m   = ws + off; off += 256;
    float* part_l   = ws + off; off += 256;
    float* part_acc = ws + off; off += 64 * 4 * 512;
    float* pg       = ws + off; off += 8 * 64 * 2048;  // aliased as Gtmp in precompute
    int*   charr    = (int*)(ws + off); off += 64;
    if (ws_size < off * sizeof(float)) return;  // workspace too small -> fail loudly

    float* Gtmp = pg;  // reuse: Gtmp only live before first step

    // ---- one-time precompute ----
    k_small<<<1, 512, 0, stream>>>(Hcw, Hcb, Icw, Icb, p0, v0, s0);
    k_P<<<dim3(2, 512), 256, 0, stream>>>(Hcw, Icw, P);
    k_G<<<dim3(2, 256), 256, 0, stream>>>(Wih, Icw, Gtmp);
    k_transpose<<<dim3(16, 64), dim3(32, 8), 0, stream>>>(Gtmp, GT, 2048, 512, 512, 0);
    k_transpose<<<dim3(16, 64), dim3(32, 8), 0, stream>>>(Whh, WhhT, 2048, 512, 512, 0);
    k_transpose<<<dim3(5, 64), dim3(32, 8), 0, stream>>>(Wih, Wih0T, 2048, 140, 652, 0);
    k_gate_bias<<<8, 256, 0, stream>>>(Wih, Icb, bih, bhh, gateb);
    k_init<<<64, 512, 0, stream>>>(lab, p0, s0, h, cst, qp, qb, charr);

    // ---- sequential decode ----
    for (int t = 0; t < TT; t++) {
        k_flash<<<dim3(4, 64), 512, 0, stream>>>(X, qp, qb, part_m, part_l, part_acc);
        k_gates<<<dim3(8, 8, 4), 256, 0, stream>>>(part_m, part_l, part_acc, h, GT, WhhT, pg);
        k_update<<<64, 256, 0, stream>>>(pg, gateb, Wih0T, Wout, bout, P, p0, v0, s0,
                                         h, cst, qp, qb, charr, out, t);
    }
}